// Round 3
// baseline (266.105 us; speedup 1.0000x reference)
//
#include <hip/hip_runtime.h>

// MultiHeadSelfAttention: B=4, T=2048, D_MODEL=768, H=12, d_k=64.
// I/O is FP32. Compute in bf16 MFMA with fp32 accum.
// v3: qkv Q/K stores staged through LDS -> coalesced 8B stores (was 16
//     scalar 2B stores/thread). flash: vf ds_reads hoisted ahead of the
//     softmax VALU phase, s_setprio around MFMA clusters (T5).

#define T_SEQ  2048
#define NH     12
#define DK     64
#define DMODEL 768
#define BATCH  4

typedef __attribute__((ext_vector_type(8))) short short8;   // 8 x bf16 MFMA frag
typedef __attribute__((ext_vector_type(4))) float f32x4;    // MFMA C/D frag
typedef __attribute__((ext_vector_type(4))) unsigned short us4;

#define CEXP (0.125f * 1.44269504088896340736f)   // 1/sqrt(d_k) * log2(e)

// HW packed fp32->bf16 (RNE), 1 instr per 2 values
__device__ __forceinline__ unsigned cvt_pk_bf16(float lo, float hi) {
  unsigned r;
  asm("v_cvt_pk_bf16_f32 %0, %1, %2" : "=v"(r) : "v"(lo), "v"(hi));
  return r;
}
__device__ __forceinline__ unsigned short f2bf1(float f) {
  unsigned r;
  asm("v_cvt_pk_bf16_f32 %0, %1, %1" : "=v"(r) : "v"(f));
  return (unsigned short)r;   // cvt_pk puts src0 in [15:0]
}
__device__ __forceinline__ us4 f4_to_bf4(float4 v) {
  union { unsigned u[2]; us4 r; } t;
  t.u[0] = cvt_pk_bf16(v.x, v.y);
  t.u[1] = cvt_pk_bf16(v.z, v.w);
  return t.r;
}

// MFMA fragment conventions (guide §3, m89/m91-verified):
//   A-frag: lane holds A[m = lane&15][k = (lane>>4)*8 + j], j=0..7
//   B-frag: lane holds B^T[n = lane&15][k = (lane>>4)*8 + j]
//   C/D:    lane holds D[row = (lane>>4)*4 + reg][col = lane&15]

// ---------------------------------------------------------------------------
// Kernel 1: per-head QKV projection, one projection per blockIdx.z.
// Q path is pre-scaled by CEXP so flash's exp2 takes raw S^T values.
// All three outputs now staged through LDS for coalesced 8B stores.
// ---------------------------------------------------------------------------
__global__ __launch_bounds__(256, 4)
void qkv_proj_kernel(const float* __restrict__ qin,
                     const float* __restrict__ kin,
                     const float* __restrict__ vin,
                     const float* __restrict__ Wq, const float* __restrict__ bq,
                     const float* __restrict__ Wk, const float* __restrict__ bk,
                     const float* __restrict__ Wv, const float* __restrict__ bv,
                     unsigned short* __restrict__ Qp,   // [bh][t][64]  (scaled)
                     unsigned short* __restrict__ Kp,   // [bh][t][64]
                     unsigned short* __restrict__ Vt)   // [bh][64][t]
{
  const int tt  = blockIdx.x;
  const int bh  = blockIdx.y;
  const int p   = blockIdx.z;
  const int b   = bh / NH, h = bh % NH;
  const int t0  = tt * 64;
  const int tid = threadIdx.x;
  const int wv  = tid >> 6;
  const int ln  = tid & 63;
  const int c   = ln & 15;
  const int qd  = ln >> 4;

  __shared__ __align__(16) unsigned short sX[64 * 72];
  __shared__ __align__(16) unsigned short sW[64 * 72];
  __shared__ __align__(16) unsigned short sO[64 * 68];   // output staging

  const float* in = (p == 0) ? qin : (p == 1) ? kin : vin;
  const float* W  = (p == 0) ? Wq  : (p == 1) ? Wk  : Wv;
  const float* bs = (p == 0) ? bq  : (p == 1) ? bk  : bv;

  const int r0 = tid >> 4, g = tid & 15;
#pragma unroll
  for (int l = 0; l < 4; ++l) {
    int r = l * 16 + r0;
    float4 xv = *reinterpret_cast<const float4*>(in + ((size_t)(b * T_SEQ + t0 + r)) * DMODEL + h * DK + g * 4);
    *reinterpret_cast<us4*>(&sX[r * 72 + g * 4]) = f4_to_bf4(xv);
    float4 wvv = *reinterpret_cast<const float4*>(W + r * DK + g * 4);
    *reinterpret_cast<us4*>(&sW[r * 72 + g * 4]) = f4_to_bf4(wvv);
  }
  __syncthreads();

  short8 af[2];
#pragma unroll
  for (int kc = 0; kc < 2; ++kc)
    af[kc] = *reinterpret_cast<const short8*>(&sX[(wv * 16 + c) * 72 + kc * 32 + qd * 8]);

  f32x4 acc[4];
#pragma unroll
  for (int nb = 0; nb < 4; ++nb) {
    f32x4 a = {0.f, 0.f, 0.f, 0.f};
#pragma unroll
    for (int kc = 0; kc < 2; ++kc) {
      short8 bf = *reinterpret_cast<const short8*>(&sW[(nb * 16 + c) * 72 + kc * 32 + qd * 8]);
      a = __builtin_amdgcn_mfma_f32_16x16x32_bf16(af[kc], bf, a, 0, 0, 0);
    }
    acc[nb] = a;
  }

  if (p < 2) {
    // stage [t_loc][n] in LDS, then coalesced 8B stores (rows of 128B)
    unsigned short* outp = (p == 0) ? Qp : Kp;
    const float sc = (p == 0) ? CEXP : 1.0f;   // fold softmax scale into Q
#pragma unroll
    for (int nb = 0; nb < 4; ++nb) {
      int n = nb * 16 + c;
      float bias = bs[n] * sc;
#pragma unroll
      for (int r = 0; r < 4; ++r) {
        int row = wv * 16 + qd * 4 + r;
        sO[row * 68 + n] = f2bf1(fmaf(acc[nb][r], sc, bias));
      }
    }
    __syncthreads();
#pragma unroll
    for (int l = 0; l < 4; ++l) {
      int r = l * 16 + r0;
      us4 val = *reinterpret_cast<const us4*>(&sO[r * 68 + g * 4]);
      *reinterpret_cast<us4*>(outp + ((size_t)bh * T_SEQ + t0 + r) * DK + g * 4) = val;
    }
  } else {
    // V: transpose through LDS, emit Vt[bh][d][t] with coalesced 8B stores
#pragma unroll
    for (int nb = 0; nb < 4; ++nb) {
      int n = nb * 16 + c;
      float bias = bs[n];
#pragma unroll
      for (int r = 0; r < 4; ++r) {
        int row = wv * 16 + qd * 4 + r;
        sO[n * 68 + row] = f2bf1(acc[nb][r] + bias);
      }
    }
    __syncthreads();
#pragma unroll
    for (int l = 0; l < 4; ++l) {
      int d = l * 16 + r0;
      us4 val = *reinterpret_cast<const us4*>(&sO[d * 68 + g * 4]);
      *reinterpret_cast<us4*>(Vt + ((size_t)bh * DK + d) * T_SEQ + t0 + g * 4) = val;
    }
  }
}

// ---------------------------------------------------------------------------
// Kernel 2: flash attention. grid (16 q-tiles of 128, 48 bh); block 256 = 4
// waves; wave owns 32 Q rows (2 A-frags). Fixed-max softmax, S^T trick.
// v3: kf+vf ds_reads issued FIRST after the barrier (reads from cur buffer
//     are safe ahead of the WRITE_BUF to the other buffer); vf latency thus
//     hides under S^T MFMA + softmax VALU. s_setprio(1) around MFMA clusters.
// LDS 36 KB; __launch_bounds__(256,3) -> 3 blocks/CU (= grid/CU exactly).
// ---------------------------------------------------------------------------
__global__ __launch_bounds__(256, 3)
void flash_kernel(const unsigned short* __restrict__ Qp,
                  const unsigned short* __restrict__ Kp,
                  const unsigned short* __restrict__ Vt,
                  unsigned short* __restrict__ concat)   // [b][t][768]
{
  // XCD-aware remap: dispatch-linear id -> (qt, bh) with 6 bh per XCD chunk
  const int lin = blockIdx.y * 16 + blockIdx.x;
  const int xcd = lin & 7;
  const int li  = lin >> 3;                 // 0..95 per XCD
  const int bh  = xcd * 6 + (li >> 4);      // 6 bh per XCD
  const int qt  = li & 15;
  const int b   = bh / NH, h = bh % NH;
  const int tid = threadIdx.x;
  const int wv  = tid >> 6;
  const int ln  = tid & 63;
  const int c   = ln & 15;
  const int qd  = ln >> 4;

  __shared__ __align__(16) unsigned short sK[2][64 * 72];   // K tile [t_loc][d]
  __shared__ __align__(16) unsigned short sV[2][64 * 72];   // V^T tile [d][t_loc]

  const int row0 = qt * 128 + wv * 32;

  // Q fragments once, straight from global (already scaled by CEXP)
  short8 qf[2][2];
#pragma unroll
  for (int f = 0; f < 2; ++f) {
    const unsigned short* qb = Qp + ((size_t)bh * T_SEQ + row0 + f * 16 + c) * DK + qd * 8;
    qf[f][0] = *reinterpret_cast<const short8*>(qb);
    qf[f][1] = *reinterpret_cast<const short8*>(qb + 32);
  }

  const int r0 = tid >> 4, g = tid & 15;
  us4 kreg[4], vreg[4];
#define LOAD_TILE(J)                                                                   \
  {                                                                                    \
    _Pragma("unroll")                                                                  \
    for (int l_ = 0; l_ < 4; ++l_) {                                                   \
      int r_ = l_ * 16 + r0;                                                           \
      kreg[l_] = *reinterpret_cast<const us4*>(Kp + ((size_t)bh * T_SEQ + (J) * 64 + r_) * DK + g * 4); \
      vreg[l_] = *reinterpret_cast<const us4*>(Vt + ((size_t)bh * DK + r_) * T_SEQ + (J) * 64 + g * 4); \
    }                                                                                  \
  }
#define WRITE_BUF(B)                                                                   \
  {                                                                                    \
    _Pragma("unroll")                                                                  \
    for (int l_ = 0; l_ < 4; ++l_) {                                                   \
      int r_ = l_ * 16 + r0;                                                           \
      *reinterpret_cast<us4*>(&sK[B][r_ * 72 + g * 4]) = kreg[l_];                     \
      *reinterpret_cast<us4*>(&sV[B][r_ * 72 + g * 4]) = vreg[l_];                     \
    }                                                                                  \
  }

  // prologue: tile0 -> buf0; prefetch tile1 into regs
  LOAD_TILE(0);
  WRITE_BUF(0);          // threads write disjoint rows; first read is after sync
  LOAD_TILE(1);

  f32x4 o[2][4];
  f32x4 lacc[2];
#pragma unroll
  for (int f = 0; f < 2; ++f) {
    lacc[f] = (f32x4){0.f, 0.f, 0.f, 0.f};
#pragma unroll
    for (int nb = 0; nb < 4; ++nb) o[f][nb] = (f32x4){0.f, 0.f, 0.f, 0.f};
  }

  short8 ones;
#pragma unroll
  for (int i = 0; i < 8; ++i) ones[i] = (short)0x3F80;   // bf16 1.0

  for (int j = 0; j < T_SEQ / 64; ++j) {
    __syncthreads();                      // buf[j&1] visible; prefetch regs drained
    const int cur = j & 1;

    // issue ALL LDS reads for this tile first: kf needed soon, vf latency
    // hides under S^T MFMA + softmax VALU (reads from cur are safe here;
    // WRITE_BUF below targets the other buffer).
    short8 kf[4][2], vf[4][2];
#pragma unroll
    for (int nb = 0; nb < 4; ++nb) {
      kf[nb][0] = *reinterpret_cast<const short8*>(&sK[cur][(nb * 16 + c) * 72 + qd * 8]);
      kf[nb][1] = *reinterpret_cast<const short8*>(&sK[cur][(nb * 16 + c) * 72 + 32 + qd * 8]);
      vf[nb][0] = *reinterpret_cast<const short8*>(&sV[cur][(nb * 16 + c) * 72 + qd * 8]);
      vf[nb][1] = *reinterpret_cast<const short8*>(&sV[cur][(nb * 16 + c) * 72 + 32 + qd * 8]);
    }

    WRITE_BUF((j + 1) & 1);               // stage tile j+1 (regs from last iter)
    LOAD_TILE((j + 2) & (T_SEQ / 64 - 1));// issue prefetch for j+2 (hidden by compute)

    // per q-frag: S^T -> exp2 -> cvt_pk -> permlane route into A-frag layout.
    // st[nb][r] = P[key = nb*16 + qd*4 + r][q = f*16 + c]   (qd = this lane's quad)
    // pf[f][kc] word w must hold keys kc*32 + qd*8 + 2w,2w+1:
    //   source lane quad = 2*(qd&1) + (w>>1), reg pk[2kc + (qd>>1)][w&1].
    // permlane32_swap: (A,B) -> A'=[A.lo,B.lo], B'=[A.hi,B.hi]
    // permlane16_swap: (A,B) -> A'=[A.r0,B.r0,A.r2,B.r2], B'=[A.r1,B.r1,A.r3,B.r3]
    // chain gives A''=[X.q0,X.q2,Y.q0,Y.q2] (word pr), B''=[X.q1,X.q3,Y.q1,Y.q3] (word 2+pr)
    short8 pf[2][2];
#pragma unroll
    for (int f = 0; f < 2; ++f) {
      f32x4 stf[4];
      __builtin_amdgcn_s_setprio(1);
#pragma unroll
      for (int nb = 0; nb < 4; ++nb) {
        f32x4 a = {0.f, 0.f, 0.f, 0.f};
        a = __builtin_amdgcn_mfma_f32_16x16x32_bf16(kf[nb][0], qf[f][0], a, 0, 0, 0);
        a = __builtin_amdgcn_mfma_f32_16x16x32_bf16(kf[nb][1], qf[f][1], a, 0, 0, 0);
        stf[nb] = a;
      }
      __builtin_amdgcn_s_setprio(0);
      unsigned pk[4][2];
#pragma unroll
      for (int nb = 0; nb < 4; ++nb) {
        float p0 = __builtin_amdgcn_exp2f(stf[nb][0]);
        float p1 = __builtin_amdgcn_exp2f(stf[nb][1]);
        float p2 = __builtin_amdgcn_exp2f(stf[nb][2]);
        float p3 = __builtin_amdgcn_exp2f(stf[nb][3]);
        pk[nb][0] = cvt_pk_bf16(p0, p1);
        pk[nb][1] = cvt_pk_bf16(p2, p3);
      }
#pragma unroll
      for (int kc = 0; kc < 2; ++kc) {
        union { unsigned w[4]; short8 s; } u;
#pragma unroll
        for (int pr = 0; pr < 2; ++pr) {
          unsigned X = pk[2 * kc][pr];      // nb = 2kc   (for target qd<2)
          unsigned Y = pk[2 * kc + 1][pr];  // nb = 2kc+1 (for target qd>=2)
          auto s32 = __builtin_amdgcn_permlane32_swap(X, Y, false, false);
          auto s16 = __builtin_amdgcn_permlane16_swap(s32[0], s32[1], false, false);
          u.w[pr]     = s16[0];   // [X.q0 X.q2 Y.q0 Y.q2]
          u.w[2 + pr] = s16[1];   // [X.q1 X.q3 Y.q1 Y.q3]
        }
        pf[f][kc] = u.s;
      }
    }

    // lsum + PV on the matrix pipe (lsum via all-ones B-frag; row mapping
    // matches o[] exactly so the epilogue needs no shuffles).
    __builtin_amdgcn_s_setprio(1);
#pragma unroll
    for (int f = 0; f < 2; ++f) {
      lacc[f] = __builtin_amdgcn_mfma_f32_16x16x32_bf16(pf[f][0], ones, lacc[f], 0, 0, 0);
      lacc[f] = __builtin_amdgcn_mfma_f32_16x16x32_bf16(pf[f][1], ones, lacc[f], 0, 0, 0);
#pragma unroll
      for (int nb = 0; nb < 4; ++nb) {
        o[f][nb] = __builtin_amdgcn_mfma_f32_16x16x32_bf16(pf[f][0], vf[nb][0], o[f][nb], 0, 0, 0);
        o[f][nb] = __builtin_amdgcn_mfma_f32_16x16x32_bf16(pf[f][1], vf[nb][1], o[f][nb], 0, 0, 0);
      }
    }
    __builtin_amdgcn_s_setprio(0);
  }

  // epilogue: lacc row mapping == o row mapping -> no shuffles needed.
#pragma unroll
  for (int f = 0; f < 2; ++f) {
    float linv[4];
#pragma unroll
    for (int r = 0; r < 4; ++r) linv[r] = __builtin_amdgcn_rcpf(lacc[f][r]);
#pragma unroll
    for (int r = 0; r < 4; ++r) {
      int t = row0 + f * 16 + qd * 4 + r;
#pragma unroll
      for (int nb = 0; nb < 4; ++nb) {
        concat[((size_t)(b * T_SEQ + t)) * DMODEL + h * DK + nb * 16 + c] =
            f2bf1(o[f][nb][r] * linv[r]);
      }
    }
  }
#undef LOAD_TILE
#undef WRITE_BUF
}

// ---------------------------------------------------------------------------
// Kernel 3: out(fp32) = concat(bf16) @ Wo^T(fp32->bf16) + bo. grid (12, 64);
// block 256 = 4 waves; wave owns 32 rows (2 A-frags). Register prefetch of
// the next K-slab overlaps global latency with MFMA.
// ---------------------------------------------------------------------------
__global__ __launch_bounds__(256, 3)
void oproj_kernel(const unsigned short* __restrict__ A,    // [8192][768] bf16
                  const float* __restrict__ Wo,            // [768][768] fp32
                  const float* __restrict__ bo,            // [768] fp32
                  float* __restrict__ out)                 // [8192][768] fp32
{
  const int nt  = blockIdx.x;
  const int mt  = blockIdx.y;       // 64 tiles of 128 rows
  const int tid = threadIdx.x;
  const int wv  = tid >> 6;
  const int ln  = tid & 63;
  const int c   = ln & 15;
  const int qd  = ln >> 4;

  __shared__ __align__(16) unsigned short sA[128 * 72];
  __shared__ __align__(16) unsigned short sB[64 * 72];

  const int r0 = tid >> 4, g = tid & 15;
  us4 areg[8];
  float4 breg[4];
#define LOAD_K(KK)                                                                       \
  {                                                                                      \
    _Pragma("unroll")                                                                    \
    for (int l = 0; l < 8; ++l)                                                          \
      areg[l] = *reinterpret_cast<const us4*>(A + ((size_t)(mt * 128 + l * 16 + r0)) * DMODEL + (KK) * 64 + g * 4); \
    _Pragma("unroll")                                                                    \
    for (int l = 0; l < 4; ++l)                                                          \
      breg[l] = *reinterpret_cast<const float4*>(Wo + ((size_t)(nt * 64 + l * 16 + r0)) * DMODEL + (KK) * 64 + g * 4); \
  }

  LOAD_K(0);

  f32x4 acc[2][4];
#pragma unroll
  for (int f = 0; f < 2; ++f)
#pragma unroll
    for (int nb = 0; nb < 4; ++nb) acc[f][nb] = (f32x4){0.f, 0.f, 0.f, 0.f};

  for (int kk = 0; kk < DMODEL / 64; ++kk) {
    __syncthreads();
#pragma unroll
    for (int l = 0; l < 8; ++l)
      *reinterpret_cast<us4*>(&sA[(l * 16 + r0) * 72 + g * 4]) = areg[l];
#pragma unroll
    for (int l = 0; l < 4; ++l)
      *reinterpret_cast<us4*>(&sB[(l * 16 + r0) * 72 + g * 4]) = f4_to_bf4(breg[l]);
    __syncthreads();

    int kn = kk + 1 < DMODEL / 64 ? kk + 1 : 0;
    LOAD_K(kn);

    short8 af[2][2];
#pragma unroll
    for (int f = 0; f < 2; ++f) {
      af[f][0] = *reinterpret_cast<const short8*>(&sA[(wv * 32 + f * 16 + c) * 72 + qd * 8]);
      af[f][1] = *reinterpret_cast<const short8*>(&sA[(wv * 32 + f * 16 + c) * 72 + 32 + qd * 8]);
    }
#pragma unroll
    for (int nb = 0; nb < 4; ++nb) {
      short8 b0 = *reinterpret_cast<const short8*>(&sB[(nb * 16 + c) * 72 + qd * 8]);
      short8 b1 = *reinterpret_cast<const short8*>(&sB[(nb * 16 + c) * 72 + 32 + qd * 8]);
#pragma unroll
      for (int f = 0; f < 2; ++f) {
        acc[f][nb] = __builtin_amdgcn_mfma_f32_16x16x32_bf16(af[f][0], b0, acc[f][nb], 0, 0, 0);
        acc[f][nb] = __builtin_amdgcn_mfma_f32_16x16x32_bf16(af[f][1], b1, acc[f][nb], 0, 0, 0);
      }
    }
  }

#pragma unroll
  for (int f = 0; f < 2; ++f)
#pragma unroll
    for (int nb = 0; nb < 4; ++nb) {
      int n = nt * 64 + nb * 16 + c;
      float bias = bo[n];
#pragma unroll
      for (int r = 0; r < 4; ++r) {
        int m = mt * 128 + wv * 32 + f * 16 + qd * 4 + r;
        out[(size_t)m * DMODEL + n] = acc[f][nb][r] + bias;
      }
    }
#undef LOAD_K
}

// ---------------------------------------------------------------------------
extern "C" void kernel_launch(void* const* d_in, const int* in_sizes, int n_in,
                              void* d_out, int out_size, void* d_ws, size_t ws_size,
                              hipStream_t stream) {
  const float* q  = (const float*)d_in[0];
  const float* k  = (const float*)d_in[1];
  const float* v  = (const float*)d_in[2];
  const float* Wq = (const float*)d_in[3];
  const float* bq = (const float*)d_in[4];
  const float* Wk = (const float*)d_in[5];
  const float* bk = (const float*)d_in[6];
  const float* Wv = (const float*)d_in[7];
  const float* bv = (const float*)d_in[8];
  const float* Wo = (const float*)d_in[9];
  const float* bo = (const float*)d_in[10];

  const size_t NTOK = (size_t)BATCH * T_SEQ;          // 8192
  const size_t PER  = NTOK * DK * NH;                 // 6291456 elems
  unsigned short* Qp     = (unsigned short*)d_ws;
  unsigned short* Kp     = Qp + PER;
  unsigned short* Vt     = Kp + PER;
  unsigned short* concat = Vt + PER;                  // total 48 MB bf16

  dim3 blk(256);
  qkv_proj_kernel<<<dim3(32, BATCH * NH, 3), blk, 0, stream>>>(q, k, v, Wq, bq, Wk, bk, Wv, bv, Qp, Kp, Vt);
  flash_kernel<<<dim3(16, BATCH * NH), blk, 0, stream>>>(Qp, Kp, Vt, concat);
  oproj_kernel<<<dim3(12, 64), blk, 0, stream>>>(concat, Wo, bo, (float*)d_out);
}

// Round 4
// 213.692 us; speedup vs baseline: 1.2453x; 1.2453x over previous
//
#include <hip/hip_runtime.h>

// MultiHeadSelfAttention: B=4, T=2048, D_MODEL=768, H=12, d_k=64.
// I/O is FP32. Compute in bf16 MFMA with fp32 accum.
// v4: flash reverted to v2 body (69 µs; v3's vf-hoist caused spill traffic
//     +22MB HBM, setprio hurt the barrier-locked regime per m190).
//     qkv restructured to 128-row tiles: 2304 blocks, 16 MFMAs/wave,
//     output staged through the sX LDS region (stride 68 / 136).

#define T_SEQ  2048
#define NH     12
#define DK     64
#define DMODEL 768
#define BATCH  4

typedef __attribute__((ext_vector_type(8))) short short8;   // 8 x bf16 MFMA frag
typedef __attribute__((ext_vector_type(4))) float f32x4;    // MFMA C/D frag
typedef __attribute__((ext_vector_type(4))) unsigned short us4;

#define CEXP (0.125f * 1.44269504088896340736f)   // 1/sqrt(d_k) * log2(e)

// HW packed fp32->bf16 (RNE), 1 instr per 2 values
__device__ __forceinline__ unsigned cvt_pk_bf16(float lo, float hi) {
  unsigned r;
  asm("v_cvt_pk_bf16_f32 %0, %1, %2" : "=v"(r) : "v"(lo), "v"(hi));
  return r;
}
__device__ __forceinline__ unsigned short f2bf1(float f) {
  unsigned r;
  asm("v_cvt_pk_bf16_f32 %0, %1, %1" : "=v"(r) : "v"(f));
  return (unsigned short)r;   // cvt_pk puts src0 in [15:0]
}
__device__ __forceinline__ us4 f4_to_bf4(float4 v) {
  union { unsigned u[2]; us4 r; } t;
  t.u[0] = cvt_pk_bf16(v.x, v.y);
  t.u[1] = cvt_pk_bf16(v.z, v.w);
  return t.r;
}

// MFMA fragment conventions (guide §3, m89/m91-verified):
//   A-frag: lane holds A[m = lane&15][k = (lane>>4)*8 + j], j=0..7
//   B-frag: lane holds B^T[n = lane&15][k = (lane>>4)*8 + j]
//   C/D:    lane holds D[row = (lane>>4)*4 + reg][col = lane&15]

// ---------------------------------------------------------------------------
// Kernel 1: per-head QKV projection, one projection per blockIdx.z.
// v4: 128 t-rows per block (grid 16 x 48 x 3), wave owns 32 rows (2 A-frags),
// 16 MFMAs/wave. Outputs staged through the sX region for coalesced stores.
// Q path pre-scaled by CEXP so flash's exp2 takes raw S^T values.
// ---------------------------------------------------------------------------
__global__ __launch_bounds__(256, 4)
void qkv_proj_kernel(const float* __restrict__ qin,
                     const float* __restrict__ kin,
                     const float* __restrict__ vin,
                     const float* __restrict__ Wq, const float* __restrict__ bq,
                     const float* __restrict__ Wk, const float* __restrict__ bk,
                     const float* __restrict__ Wv, const float* __restrict__ bv,
                     unsigned short* __restrict__ Qp,   // [bh][t][64]  (scaled)
                     unsigned short* __restrict__ Kp,   // [bh][t][64]
                     unsigned short* __restrict__ Vt)   // [bh][64][t]
{
  const int tt  = blockIdx.x;
  const int bh  = blockIdx.y;
  const int p   = blockIdx.z;
  const int b   = bh / NH, h = bh % NH;
  const int t0  = tt * 128;
  const int tid = threadIdx.x;
  const int wv  = tid >> 6;
  const int ln  = tid & 63;
  const int c   = ln & 15;
  const int qd  = ln >> 4;

  __shared__ __align__(16) unsigned short sX[128 * 72];  // input tile; reused as output staging
  __shared__ __align__(16) unsigned short sW[64 * 72];

  const float* in = (p == 0) ? qin : (p == 1) ? kin : vin;
  const float* W  = (p == 0) ? Wq  : (p == 1) ? Wk  : Wv;
  const float* bs = (p == 0) ? bq  : (p == 1) ? bk  : bv;

  const int r0 = tid >> 4, g = tid & 15;
#pragma unroll
  for (int l = 0; l < 8; ++l) {
    int r = l * 16 + r0;
    float4 xv = *reinterpret_cast<const float4*>(in + ((size_t)(b * T_SEQ + t0 + r)) * DMODEL + h * DK + g * 4);
    *reinterpret_cast<us4*>(&sX[r * 72 + g * 4]) = f4_to_bf4(xv);
  }
#pragma unroll
  for (int l = 0; l < 4; ++l) {
    int r = l * 16 + r0;
    float4 wvv = *reinterpret_cast<const float4*>(W + r * DK + g * 4);
    *reinterpret_cast<us4*>(&sW[r * 72 + g * 4]) = f4_to_bf4(wvv);
  }
  __syncthreads();

  short8 af[2][2];
#pragma unroll
  for (int f = 0; f < 2; ++f)
#pragma unroll
    for (int kc = 0; kc < 2; ++kc)
      af[f][kc] = *reinterpret_cast<const short8*>(&sX[(wv * 32 + f * 16 + c) * 72 + kc * 32 + qd * 8]);

  f32x4 acc[2][4];
#pragma unroll
  for (int nb = 0; nb < 4; ++nb) {
    short8 b0 = *reinterpret_cast<const short8*>(&sW[(nb * 16 + c) * 72 + qd * 8]);
    short8 b1 = *reinterpret_cast<const short8*>(&sW[(nb * 16 + c) * 72 + 32 + qd * 8]);
#pragma unroll
    for (int f = 0; f < 2; ++f) {
      f32x4 a = {0.f, 0.f, 0.f, 0.f};
      a = __builtin_amdgcn_mfma_f32_16x16x32_bf16(af[f][0], b0, a, 0, 0, 0);
      a = __builtin_amdgcn_mfma_f32_16x16x32_bf16(af[f][1], b1, a, 0, 0, 0);
      acc[f][nb] = a;
    }
  }

  __syncthreads();   // all sX/sW reads done -> safe to reuse sX as staging

  if (p < 2) {
    // stage [row][n] (stride 68: 2-way-free banks), then coalesced 8B stores
    unsigned short* outp = (p == 0) ? Qp : Kp;
    const float sc = (p == 0) ? CEXP : 1.0f;   // fold softmax scale into Q
#pragma unroll
    for (int f = 0; f < 2; ++f)
#pragma unroll
      for (int nb = 0; nb < 4; ++nb) {
        int n = nb * 16 + c;
        float bias = bs[n] * sc;
#pragma unroll
        for (int r = 0; r < 4; ++r) {
          int row = wv * 32 + f * 16 + qd * 4 + r;
          sX[row * 68 + n] = f2bf1(fmaf(acc[f][nb][r], sc, bias));
        }
      }
    __syncthreads();
#pragma unroll
    for (int l = 0; l < 8; ++l) {
      int idx = l * 256 + tid;
      int r  = idx >> 4;          // 0..127
      int g2 = idx & 15;          // 0..15
      us4 val = *reinterpret_cast<const us4*>(&sX[r * 68 + g2 * 4]);
      *reinterpret_cast<us4*>(outp + ((size_t)bh * T_SEQ + t0 + r) * DK + g2 * 4) = val;
    }
  } else {
    // V: transpose in sX region [d][t_loc] (stride 136), coalesced 8B stores
#pragma unroll
    for (int f = 0; f < 2; ++f)
#pragma unroll
      for (int nb = 0; nb < 4; ++nb) {
        int n = nb * 16 + c;
        float bias = bs[n];
#pragma unroll
        for (int r = 0; r < 4; ++r) {
          int row = wv * 32 + f * 16 + qd * 4 + r;
          sX[n * 136 + row] = f2bf1(acc[f][nb][r] + bias);
        }
      }
    __syncthreads();
#pragma unroll
    for (int l = 0; l < 8; ++l) {
      int idx = l * 256 + tid;
      int d  = idx >> 5;          // 0..63
      int gg = idx & 31;          // 0..31 (us4 units across 128 t)
      us4 val = *reinterpret_cast<const us4*>(&sX[d * 136 + gg * 4]);
      *reinterpret_cast<us4*>(Vt + ((size_t)bh * DK + d) * T_SEQ + t0 + gg * 4) = val;
    }
  }
}

// ---------------------------------------------------------------------------
// Kernel 2: flash attention (v2 body, verbatim — 69 µs measured).
// grid (16 q-tiles of 128, 48 bh); block 256 = 4 waves; wave owns 32 Q rows.
// Fixed-max softmax, S^T trick, in-register P via cvt_pk + permlane swaps,
// lsum via ones-MFMA, single-barrier K/V double-buffer, XCD-aware bh map.
// ---------------------------------------------------------------------------
__global__ __launch_bounds__(256, 3)
void flash_kernel(const unsigned short* __restrict__ Qp,
                  const unsigned short* __restrict__ Kp,
                  const unsigned short* __restrict__ Vt,
                  unsigned short* __restrict__ concat)   // [b][t][768]
{
  // XCD-aware remap: dispatch-linear id -> (qt, bh) with 6 bh per XCD chunk
  const int lin = blockIdx.y * 16 + blockIdx.x;
  const int xcd = lin & 7;
  const int li  = lin >> 3;                 // 0..95 per XCD
  const int bh  = xcd * 6 + (li >> 4);      // 6 bh per XCD
  const int qt  = li & 15;
  const int b   = bh / NH, h = bh % NH;
  const int tid = threadIdx.x;
  const int wv  = tid >> 6;
  const int ln  = tid & 63;
  const int c   = ln & 15;
  const int qd  = ln >> 4;

  __shared__ __align__(16) unsigned short sK[2][64 * 72];   // K tile [t_loc][d]
  __shared__ __align__(16) unsigned short sV[2][64 * 72];   // V^T tile [d][t_loc]

  const int row0 = qt * 128 + wv * 32;

  // Q fragments once, straight from global (already scaled by CEXP)
  short8 qf[2][2];
#pragma unroll
  for (int f = 0; f < 2; ++f) {
    const unsigned short* qb = Qp + ((size_t)bh * T_SEQ + row0 + f * 16 + c) * DK + qd * 8;
    qf[f][0] = *reinterpret_cast<const short8*>(qb);
    qf[f][1] = *reinterpret_cast<const short8*>(qb + 32);
  }

  const int r0 = tid >> 4, g = tid & 15;
  us4 kreg[4], vreg[4];
#define LOAD_TILE(J)                                                                   \
  {                                                                                    \
    _Pragma("unroll")                                                                  \
    for (int l_ = 0; l_ < 4; ++l_) {                                                   \
      int r_ = l_ * 16 + r0;                                                           \
      kreg[l_] = *reinterpret_cast<const us4*>(Kp + ((size_t)bh * T_SEQ + (J) * 64 + r_) * DK + g * 4); \
      vreg[l_] = *reinterpret_cast<const us4*>(Vt + ((size_t)bh * DK + r_) * T_SEQ + (J) * 64 + g * 4); \
    }                                                                                  \
  }
#define WRITE_BUF(B)                                                                   \
  {                                                                                    \
    _Pragma("unroll")                                                                  \
    for (int l_ = 0; l_ < 4; ++l_) {                                                   \
      int r_ = l_ * 16 + r0;                                                           \
      *reinterpret_cast<us4*>(&sK[B][r_ * 72 + g * 4]) = kreg[l_];                     \
      *reinterpret_cast<us4*>(&sV[B][r_ * 72 + g * 4]) = vreg[l_];                     \
    }                                                                                  \
  }

  // prologue: tile0 -> buf0; prefetch tile1 into regs
  LOAD_TILE(0);
  WRITE_BUF(0);          // threads write disjoint rows; first read is after sync
  LOAD_TILE(1);

  f32x4 o[2][4];
  f32x4 lacc[2];
#pragma unroll
  for (int f = 0; f < 2; ++f) {
    lacc[f] = (f32x4){0.f, 0.f, 0.f, 0.f};
#pragma unroll
    for (int nb = 0; nb < 4; ++nb) o[f][nb] = (f32x4){0.f, 0.f, 0.f, 0.f};
  }

  short8 ones;
#pragma unroll
  for (int i = 0; i < 8; ++i) ones[i] = (short)0x3F80;   // bf16 1.0

  for (int j = 0; j < T_SEQ / 64; ++j) {
    __syncthreads();                      // buf[j&1] visible; prefetch regs drained
    const int cur = j & 1;
    WRITE_BUF((j + 1) & 1);               // stage tile j+1 (regs from last iter)
    LOAD_TILE((j + 2) & (T_SEQ / 64 - 1));// issue prefetch for j+2 (hidden by compute)

    // K fragments (A-operand of S^T), shared across both q-frags
    short8 kf[4][2];
#pragma unroll
    for (int nb = 0; nb < 4; ++nb) {
      kf[nb][0] = *reinterpret_cast<const short8*>(&sK[cur][(nb * 16 + c) * 72 + qd * 8]);
      kf[nb][1] = *reinterpret_cast<const short8*>(&sK[cur][(nb * 16 + c) * 72 + 32 + qd * 8]);
    }

    // per q-frag: S^T -> exp2 -> cvt_pk -> permlane route into A-frag layout.
    // st[nb][r] = P[key = nb*16 + qd*4 + r][q = f*16 + c]   (qd = this lane's quad)
    // pf[f][kc] word w must hold keys kc*32 + qd*8 + 2w,2w+1:
    //   source lane quad = 2*(qd&1) + (w>>1), reg pk[2kc + (qd>>1)][w&1].
    // permlane32_swap: (A,B) -> A'=[A.lo,B.lo], B'=[A.hi,B.hi]
    // permlane16_swap: (A,B) -> A'=[A.r0,B.r0,A.r2,B.r2], B'=[A.r1,B.r1,A.r3,B.r3]
    // chain gives A''=[X.q0,X.q2,Y.q0,Y.q2] (word pr), B''=[X.q1,X.q3,Y.q1,Y.q3] (word 2+pr)
    short8 pf[2][2];
#pragma unroll
    for (int f = 0; f < 2; ++f) {
      f32x4 stf[4];
#pragma unroll
      for (int nb = 0; nb < 4; ++nb) {
        f32x4 a = {0.f, 0.f, 0.f, 0.f};
        a = __builtin_amdgcn_mfma_f32_16x16x32_bf16(kf[nb][0], qf[f][0], a, 0, 0, 0);
        a = __builtin_amdgcn_mfma_f32_16x16x32_bf16(kf[nb][1], qf[f][1], a, 0, 0, 0);
        stf[nb] = a;
      }
      unsigned pk[4][2];
#pragma unroll
      for (int nb = 0; nb < 4; ++nb) {
        float p0 = __builtin_amdgcn_exp2f(stf[nb][0]);
        float p1 = __builtin_amdgcn_exp2f(stf[nb][1]);
        float p2 = __builtin_amdgcn_exp2f(stf[nb][2]);
        float p3 = __builtin_amdgcn_exp2f(stf[nb][3]);
        pk[nb][0] = cvt_pk_bf16(p0, p1);
        pk[nb][1] = cvt_pk_bf16(p2, p3);
      }
#pragma unroll
      for (int kc = 0; kc < 2; ++kc) {
        union { unsigned w[4]; short8 s; } u;
#pragma unroll
        for (int pr = 0; pr < 2; ++pr) {
          unsigned X = pk[2 * kc][pr];      // nb = 2kc   (for target qd<2)
          unsigned Y = pk[2 * kc + 1][pr];  // nb = 2kc+1 (for target qd>=2)
          auto s32 = __builtin_amdgcn_permlane32_swap(X, Y, false, false);
          auto s16 = __builtin_amdgcn_permlane16_swap(s32[0], s32[1], false, false);
          u.w[pr]     = s16[0];   // [X.q0 X.q2 Y.q0 Y.q2]
          u.w[2 + pr] = s16[1];   // [X.q1 X.q3 Y.q1 Y.q3]
        }
        pf[f][kc] = u.s;
      }
    }

    // V^T fragments (B-operand), shared across both q-frags
    short8 vf[4][2];
#pragma unroll
    for (int nb = 0; nb < 4; ++nb) {
      vf[nb][0] = *reinterpret_cast<const short8*>(&sV[cur][(nb * 16 + c) * 72 + qd * 8]);
      vf[nb][1] = *reinterpret_cast<const short8*>(&sV[cur][(nb * 16 + c) * 72 + 32 + qd * 8]);
    }

    // lsum on the matrix pipe: rowsum(P) with an all-ones B-frag.
#pragma unroll
    for (int f = 0; f < 2; ++f) {
      lacc[f] = __builtin_amdgcn_mfma_f32_16x16x32_bf16(pf[f][0], ones, lacc[f], 0, 0, 0);
      lacc[f] = __builtin_amdgcn_mfma_f32_16x16x32_bf16(pf[f][1], ones, lacc[f], 0, 0, 0);
    }

#pragma unroll
    for (int f = 0; f < 2; ++f)
#pragma unroll
      for (int nb = 0; nb < 4; ++nb) {
        o[f][nb] = __builtin_amdgcn_mfma_f32_16x16x32_bf16(pf[f][0], vf[nb][0], o[f][nb], 0, 0, 0);
        o[f][nb] = __builtin_amdgcn_mfma_f32_16x16x32_bf16(pf[f][1], vf[nb][1], o[f][nb], 0, 0, 0);
      }
  }

  // epilogue: lacc row mapping == o row mapping -> no shuffles needed.
#pragma unroll
  for (int f = 0; f < 2; ++f) {
    float linv[4];
#pragma unroll
    for (int r = 0; r < 4; ++r) linv[r] = __builtin_amdgcn_rcpf(lacc[f][r]);
#pragma unroll
    for (int r = 0; r < 4; ++r) {
      int t = row0 + f * 16 + qd * 4 + r;
#pragma unroll
      for (int nb = 0; nb < 4; ++nb) {
        concat[((size_t)(b * T_SEQ + t)) * DMODEL + h * DK + nb * 16 + c] =
            f2bf1(o[f][nb][r] * linv[r]);
      }
    }
  }
#undef LOAD_TILE
#undef WRITE_BUF
}

// ---------------------------------------------------------------------------
// Kernel 3: out(fp32) = concat(bf16) @ Wo^T(fp32->bf16) + bo. grid (12, 64);
// block 256 = 4 waves; wave owns 32 rows (2 A-frags). Register prefetch of
// the next K-slab overlaps global latency with MFMA.
// ---------------------------------------------------------------------------
__global__ __launch_bounds__(256, 3)
void oproj_kernel(const unsigned short* __restrict__ A,    // [8192][768] bf16
                  const float* __restrict__ Wo,            // [768][768] fp32
                  const float* __restrict__ bo,            // [768] fp32
                  float* __restrict__ out)                 // [8192][768] fp32
{
  const int nt  = blockIdx.x;
  const int mt  = blockIdx.y;       // 64 tiles of 128 rows
  const int tid = threadIdx.x;
  const int wv  = tid >> 6;
  const int ln  = tid & 63;
  const int c   = ln & 15;
  const int qd  = ln >> 4;

  __shared__ __align__(16) unsigned short sA[128 * 72];
  __shared__ __align__(16) unsigned short sB[64 * 72];

  const int r0 = tid >> 4, g = tid & 15;
  us4 areg[8];
  float4 breg[4];
#define LOAD_K(KK)                                                                       \
  {                                                                                      \
    _Pragma("unroll")                                                                    \
    for (int l = 0; l < 8; ++l)                                                          \
      areg[l] = *reinterpret_cast<const us4*>(A + ((size_t)(mt * 128 + l * 16 + r0)) * DMODEL + (KK) * 64 + g * 4); \
    _Pragma("unroll")                                                                    \
    for (int l = 0; l < 4; ++l)                                                          \
      breg[l] = *reinterpret_cast<const float4*>(Wo + ((size_t)(nt * 64 + l * 16 + r0)) * DMODEL + (KK) * 64 + g * 4); \
  }

  LOAD_K(0);

  f32x4 acc[2][4];
#pragma unroll
  for (int f = 0; f < 2; ++f)
#pragma unroll
    for (int nb = 0; nb < 4; ++nb) acc[f][nb] = (f32x4){0.f, 0.f, 0.f, 0.f};

  for (int kk = 0; kk < DMODEL / 64; ++kk) {
    __syncthreads();
#pragma unroll
    for (int l = 0; l < 8; ++l)
      *reinterpret_cast<us4*>(&sA[(l * 16 + r0) * 72 + g * 4]) = areg[l];
#pragma unroll
    for (int l = 0; l < 4; ++l)
      *reinterpret_cast<us4*>(&sB[(l * 16 + r0) * 72 + g * 4]) = f4_to_bf4(breg[l]);
    __syncthreads();

    int kn = kk + 1 < DMODEL / 64 ? kk + 1 : 0;
    LOAD_K(kn);

    short8 af[2][2];
#pragma unroll
    for (int f = 0; f < 2; ++f) {
      af[f][0] = *reinterpret_cast<const short8*>(&sA[(wv * 32 + f * 16 + c) * 72 + qd * 8]);
      af[f][1] = *reinterpret_cast<const short8*>(&sA[(wv * 32 + f * 16 + c) * 72 + 32 + qd * 8]);
    }
#pragma unroll
    for (int nb = 0; nb < 4; ++nb) {
      short8 b0 = *reinterpret_cast<const short8*>(&sB[(nb * 16 + c) * 72 + qd * 8]);
      short8 b1 = *reinterpret_cast<const short8*>(&sB[(nb * 16 + c) * 72 + 32 + qd * 8]);
#pragma unroll
      for (int f = 0; f < 2; ++f) {
        acc[f][nb] = __builtin_amdgcn_mfma_f32_16x16x32_bf16(af[f][0], b0, acc[f][nb], 0, 0, 0);
        acc[f][nb] = __builtin_amdgcn_mfma_f32_16x16x32_bf16(af[f][1], b1, acc[f][nb], 0, 0, 0);
      }
    }
  }

#pragma unroll
  for (int f = 0; f < 2; ++f)
#pragma unroll
    for (int nb = 0; nb < 4; ++nb) {
      int n = nt * 64 + nb * 16 + c;
      float bias = bo[n];
#pragma unroll
      for (int r = 0; r < 4; ++r) {
        int m = mt * 128 + wv * 32 + f * 16 + qd * 4 + r;
        out[(size_t)m * DMODEL + n] = acc[f][nb][r] + bias;
      }
    }
#undef LOAD_K
}

// ---------------------------------------------------------------------------
extern "C" void kernel_launch(void* const* d_in, const int* in_sizes, int n_in,
                              void* d_out, int out_size, void* d_ws, size_t ws_size,
                              hipStream_t stream) {
  const float* q  = (const float*)d_in[0];
  const float* k  = (const float*)d_in[1];
  const float* v  = (const float*)d_in[2];
  const float* Wq = (const float*)d_in[3];
  const float* bq = (const float*)d_in[4];
  const float* Wk = (const float*)d_in[5];
  const float* bk = (const float*)d_in[6];
  const float* Wv = (const float*)d_in[7];
  const float* bv = (const float*)d_in[8];
  const float* Wo = (const float*)d_in[9];
  const float* bo = (const float*)d_in[10];

  const size_t NTOK = (size_t)BATCH * T_SEQ;          // 8192
  const size_t PER  = NTOK * DK * NH;                 // 6291456 elems
  unsigned short* Qp     = (unsigned short*)d_ws;
  unsigned short* Kp     = Qp + PER;
  unsigned short* Vt     = Kp + PER;
  unsigned short* concat = Vt + PER;                  // total 48 MB bf16

  dim3 blk(256);
  qkv_proj_kernel<<<dim3(16, BATCH * NH, 3), blk, 0, stream>>>(q, k, v, Wq, bq, Wk, bk, Wv, bv, Qp, Kp, Vt);
  flash_kernel<<<dim3(16, BATCH * NH), blk, 0, stream>>>(Qp, Kp, Vt, concat);
  oproj_kernel<<<dim3(12, 64), blk, 0, stream>>>(concat, Wo, bo, (float*)d_out);
}